// Round 4
// baseline (3429.750 us; speedup 1.0000x reference)
//
#include <hip/hip_runtime.h>

typedef __attribute__((ext_vector_type(8))) short short8;
typedef __attribute__((ext_vector_type(4))) float f32x4;

#define SEQ_BLOCKS 64

__device__ __forceinline__ unsigned short f2bf(float f) {
  unsigned u = __float_as_uint(f);
  u = u + 0x7fffu + ((u >> 16) & 1u);
  return (unsigned short)(u >> 16);
}
__device__ __forceinline__ unsigned short f2h(float f) {
  _Float16 h = (_Float16)f;
  unsigned short r;
  __builtin_memcpy(&r, &h, 2);
  return r;
}
__device__ __forceinline__ float h2f(unsigned short u) {
  _Float16 h;
  __builtin_memcpy(&h, &u, 2);
  return (float)h;
}
__device__ __forceinline__ void gload16(const void* g, void* l) {
  __builtin_amdgcn_global_load_lds(
      (const __attribute__((address_space(1))) unsigned int*)g,
      (__attribute__((address_space(3))) unsigned int*)l, 16, 0, 0);
}
__device__ __forceinline__ float fast_sigmoid(float x) {
  return 1.0f / (1.0f + __expf(-x));
}
__device__ __forceinline__ float fast_tanh(float x) {
  return 2.0f / (1.0f + __expf(-2.0f * x)) - 1.0f;
}
// 16B load that bypasses L1/L2 (relaxed agent atomics -> sc0 sc1, no inv/wbl2)
__device__ __forceinline__ short8 load_h16(const unsigned short* p) {
  union { unsigned long long u[2]; short8 s; } r;
  r.u[0] = __hip_atomic_load((const unsigned long long*)p, __ATOMIC_RELAXED,
                             __HIP_MEMORY_SCOPE_AGENT);
  r.u[1] = __hip_atomic_load(((const unsigned long long*)p) + 1, __ATOMIC_RELAXED,
                             __HIP_MEMORY_SCOPE_AGENT);
  return r.s;
}

// ---------- elementwise fp32 -> bf16 convert (vectorized) ----------
__global__ void k_conv_bf16(const float* __restrict__ in, unsigned short* __restrict__ out) {
  size_t i = ((size_t)blockIdx.x * 256 + threadIdx.x) * 4;
  float4 v = *(const float4*)(in + i);
  unsigned short o[4] = {f2bf(v.x), f2bf(v.y), f2bf(v.z), f2bf(v.w)};
  *(uint2*)(out + i) = *(const uint2*)o;
}

// ---------- transpose + convert: out[c][r] = bf16(in[r][c]) ----------
__global__ void k_transpose(const float* __restrict__ in, unsigned short* __restrict__ out,
                            int R, int C) {
  __shared__ float tile[32][33];
  int bx = blockIdx.x * 32, by = blockIdx.y * 32;
  int tx = threadIdx.x & 31, ty = threadIdx.x >> 5;  // ty 0..7
  for (int i = 0; i < 32; i += 8)
    tile[ty + i][tx] = in[(size_t)(by + ty + i) * C + bx + tx];
  __syncthreads();
  for (int i = 0; i < 32; i += 8)
    out[(size_t)(bx + ty + i) * R + by + tx] = f2bf(tile[tx][ty + i]);
}

// ---------- generic bf16 GEMM, C = A @ B^T (+bias), A[M][K], B[N][K] bf16 ----------
// OUTMODE 0: bf16 linear C[row][col]
// OUTMODE 1: fp16 tiled GX2[t][blk][g][b][jj]  (row = t*64+b, col = g*1024 + blk*16 + jj)
template<int OUTMODE>
__global__ __launch_bounds__(256) void k_gemm_bt(
    const unsigned short* __restrict__ A, const unsigned short* __restrict__ B,
    unsigned short* __restrict__ C, const float* __restrict__ bias,
    int M, int N, int K) {
  __shared__ unsigned short As[128 * 32];
  __shared__ unsigned short Bs[128 * 32];
  const int tid = threadIdx.x;
  const int wv = tid >> 6, l = tid & 63;
  const int m0 = blockIdx.y * 128, n0 = blockIdx.x * 128;
  const int wr = (wv >> 1) * 64, wc = (wv & 1) * 64;
  f32x4 acc[4][4] = {};
  for (int k0 = 0; k0 < K; k0 += 32) {
#pragma unroll
    for (int j = 0; j < 2; ++j) {
      int c = wv * 128 + j * 64 + l;
      int row = c >> 2, kc = (c & 3) * 8;
      gload16(A + (size_t)(m0 + row) * K + k0 + kc, (char*)As + c * 16);
      gload16(B + (size_t)(n0 + row) * K + k0 + kc, (char*)Bs + c * 16);
    }
    __syncthreads();
    short8 af[4], bfr[4];
#pragma unroll
    for (int rf = 0; rf < 4; ++rf)
      af[rf] = *(const short8*)(As + (wr + rf * 16 + (l & 15)) * 32 + (l >> 4) * 8);
#pragma unroll
    for (int cf = 0; cf < 4; ++cf)
      bfr[cf] = *(const short8*)(Bs + (wc + cf * 16 + (l & 15)) * 32 + (l >> 4) * 8);
#pragma unroll
    for (int rf = 0; rf < 4; ++rf)
#pragma unroll
      for (int cf = 0; cf < 4; ++cf)
        acc[rf][cf] = __builtin_amdgcn_mfma_f32_16x16x32_bf16(af[rf], bfr[cf], acc[rf][cf], 0, 0, 0);
    __syncthreads();
  }
#pragma unroll
  for (int cf = 0; cf < 4; ++cf) {
    int col = n0 + wc + cf * 16 + (l & 15);
    float bv = bias ? bias[col] : 0.0f;
#pragma unroll
    for (int rf = 0; rf < 4; ++rf) {
#pragma unroll
      for (int i = 0; i < 4; ++i) {
        int row = m0 + wr + rf * 16 + (l >> 4) * 4 + i;
        float v = acc[rf][cf][i] + bv;
        if (OUTMODE == 0) {
          C[(size_t)row * N + col] = f2bf(v);
        } else {
          int t = row >> 6, b = row & 63;
          int g = col >> 10, c = col & 1023;
          size_t idx = (size_t)(t * 64 + (c >> 4)) * 4096 + (g * 64 + b) * 16 + (c & 15);
          C[idx] = f2h(v);
        }
      }
    }
  }
}

// ---------- combined bias ----------
__global__ void k_bias(const float* __restrict__ Wxg, const float* __restrict__ bxg,
                       const float* __restrict__ b_in, const float* __restrict__ Whg,
                       const float* __restrict__ bhg, const float* __restrict__ b_hid,
                       float* __restrict__ gbias) {
  int col = blockIdx.x * 64 + (threadIdx.x >> 2);
  int p = threadIdx.x & 3;
  const float* wx = Wxg + (size_t)col * 1024;
  const float* wh = Whg + (size_t)col * 1024;
  float s = 0.f;
  for (int k = p * 256; k < p * 256 + 256; ++k)
    s += wx[k] * b_in[k] + wh[k] * b_hid[k];
  s += __shfl_down(s, 2, 4);
  s += __shfl_down(s, 1, 4);
  if (p == 0) gbias[col] = s + bxg[col] + bhg[col];
}

// ---------- persistent sequential LSTM scan (wave-autonomous) ----------
// 64 blocks x 4 waves. Block owns h-cols [bid*16,+16); wave wv owns b-rows
// [wv*16,+16). Everything a wave needs (its A rows, its gate rows, its
// elementwise rows) stays inside the wave -> ZERO block-wide barriers in the
// loop. Sync: per-(wave,block) flags at 4KB stride; wave wv polls the 64
// same-wv flags. All cross-block data moves via L3 (sc0 sc1 atomics).
__global__ __launch_bounds__(256, 1) void k_lstm_seq(
    const unsigned short* __restrict__ GX2,  // fp16 tiled [256][64][4][64][16]
    const unsigned short* __restrict__ Whc,  // bf16 [4096][1024]
    const float* __restrict__ cell,          // [64][1024] f32
    unsigned short* __restrict__ hbuf,       // bf16 [2][64][1024]
    float* __restrict__ out,                 // h [64][1024], c [64][1024] f32
    unsigned* __restrict__ flags) {          // [(wv*64+bid)*1024] u32, 4KB apart
  __shared__ unsigned short Wl[64 * 1024];   // 128 KB, XOR-swizzled
  __shared__ float gbuf[64 * 68];            // [b][4*16 gate-cols], stride 68
  const int tid = threadIdx.x;
  const int wv = tid >> 6, l = tid & 63;
  const int bid = blockIdx.x;

  // stage weight slice into LDS, XOR swizzle: byte = c*2048 + (kbyte ^ ((c&7)<<4))
  for (int c = wv; c < 64; c += 4) {
    const unsigned short* src = Whc + (size_t)((c >> 4) * 1024 + bid * 16 + (c & 15)) * 1024;
    int cx = (c & 7) << 4;
#pragma unroll
    for (int kk = 0; kk < 2; ++kk) {
      int chunk = l + kk * 64;  // 0..127 chunks of 16B
      short8 v = *(const short8*)(src + chunk * 8);
      *(short8*)((char*)Wl + c * 2048 + ((chunk * 16) ^ cx)) = v;
    }
  }
  // elementwise ownership (wave-aligned): row eb = wv*16 + (l>>2), cols ej..ej+3
  const int eb = wv * 16 + (l >> 2);
  const int ej = (l & 3) * 4;
  float c_reg[4];
  {
    float4 c4 = *(const float4*)(cell + (size_t)eb * 1024 + bid * 16 + ej);
    c_reg[0] = c4.x; c_reg[1] = c4.y; c_reg[2] = c4.z; c_reg[3] = c4.w;
  }
  __syncthreads();  // Wl ready — the ONLY block-wide barrier

  const int cxor = ((l & 15) & 7) << 4;
  const int lrow = wv * 16 + (l & 15);       // A-row this lane feeds
  const int khalf = (l >> 4) * 8;            // k sub-offset within fragment
  unsigned* myflag = flags + (size_t)(wv * 64 + bid) * 1024;
  const unsigned* pollflag = flags + (size_t)(wv * 64 + l) * 1024;

  for (int t = 0; t < 256; ++t) {
    // --- prefetch x-path preactivation (tiled GX2: one 128B line per instr) ---
    const unsigned short* chunk = GX2 + ((size_t)t * 64 + bid) * 4096;
    unsigned short gxv[16];
#pragma unroll
    for (int cf = 0; cf < 4; ++cf)
#pragma unroll
      for (int i = 0; i < 4; ++i)
        gxv[cf * 4 + i] = chunk[(cf * 64 + wv * 16 + (l >> 4) * 4 + i) * 16 + (l & 15)];

    // --- wait for h(t) rows [wv*16,+16): poll the 64 same-wv flags ---
    if (t > 0) {
      const unsigned tgt = (unsigned)t;
      for (;;) {
        unsigned v = __hip_atomic_load(pollflag, __ATOMIC_RELAXED, __HIP_MEMORY_SCOPE_AGENT);
        if (__all((int)(v >= tgt))) break;
      }
      __builtin_amdgcn_fence(__ATOMIC_ACQUIRE, "workgroup");
    }

    // --- load wave's A rows (16 x 1024 bf16) straight from L3 ---
    const unsigned short* hbase = hbuf + (t & 1) * 65536 + (size_t)lrow * 1024 + khalf;
    short8 a[32];
#pragma unroll
    for (int u = 0; u < 32; ++u) a[u] = load_h16(hbase + u * 32);

    // --- 128 MFMA: acc[cf] over all 64 gate-cols of this block ---
    f32x4 acc[4] = {};
#pragma unroll
    for (int u = 0; u < 32; ++u) {
#pragma unroll
      for (int cf = 0; cf < 4; ++cf) {
        short8 bb = *(const short8*)((const char*)Wl + (cf * 16 + (l & 15)) * 2048 +
                                     ((khalf * 2 + u * 64) ^ cxor));
        acc[cf] = __builtin_amdgcn_mfma_f32_16x16x32_bf16(a[u], bb, acc[cf], 0, 0, 0);
      }
    }

    // --- intra-wave gate exchange via LDS (rows wv*16..+16 are wave-private) ---
#pragma unroll
    for (int cf = 0; cf < 4; ++cf)
#pragma unroll
      for (int i = 0; i < 4; ++i)
        gbuf[(wv * 16 + (l >> 4) * 4 + i) * 68 + cf * 16 + (l & 15)] =
            acc[cf][i] + h2f(gxv[cf * 4 + i]);
    asm volatile("s_waitcnt lgkmcnt(0)" ::: "memory");
    __builtin_amdgcn_sched_barrier(0);

    // --- elementwise update: thread owns (eb, ej..ej+3) ---
    float hnew[4];
#pragma unroll
    for (int i = 0; i < 4; ++i) {
      float vi = gbuf[eb * 68 + ej + i];
      float vf = gbuf[eb * 68 + 16 + ej + i];
      float vg = gbuf[eb * 68 + 32 + ej + i];
      float vo = gbuf[eb * 68 + 48 + ej + i];
      float ig = fast_sigmoid(vi);
      float fg = fast_sigmoid(vf);
      float gg = fast_tanh(vg);
      float og = fast_sigmoid(vo);
      c_reg[i] = fg * c_reg[i] + ig * gg;
      hnew[i] = og * fast_tanh(c_reg[i]);
    }

    if (t == 255) {
      float4 h4 = {hnew[0], hnew[1], hnew[2], hnew[3]};
      float4 c4 = {c_reg[0], c_reg[1], c_reg[2], c_reg[3]};
      *(float4*)(out + (size_t)eb * 1024 + bid * 16 + ej) = h4;
      *(float4*)(out + 65536 + (size_t)eb * 1024 + bid * 16 + ej) = c4;
    } else {
      // write-through h(t+1) to L3 (packed u64, relaxed agent = sc0 sc1)
      unsigned short hs[4] = {f2bf(hnew[0]), f2bf(hnew[1]), f2bf(hnew[2]), f2bf(hnew[3])};
      unsigned long long hv;
      __builtin_memcpy(&hv, hs, 8);
      __hip_atomic_store(
          (unsigned long long*)(hbuf + ((t + 1) & 1) * 65536 + (size_t)eb * 1024 + bid * 16 + ej),
          hv, __ATOMIC_RELAXED, __HIP_MEMORY_SCOPE_AGENT);
      asm volatile("s_waitcnt vmcnt(0)" ::: "memory");  // wave's h-stores at L3
      if (l == 0)
        __hip_atomic_store(myflag, (unsigned)(t + 1), __ATOMIC_RELAXED,
                           __HIP_MEMORY_SCOPE_AGENT);
    }
  }
}

extern "C" void kernel_launch(void* const* d_in, const int* in_sizes, int n_in,
                              void* d_out, int out_size, void* d_ws, size_t ws_size,
                              hipStream_t stream) {
  const float* x      = (const float*)d_in[0];
  const float* hidden = (const float*)d_in[1];
  const float* cell   = (const float*)d_in[2];
  const float* W_in   = (const float*)d_in[3];
  const float* b_in   = (const float*)d_in[4];
  const float* W_hid  = (const float*)d_in[5];
  const float* b_hid  = (const float*)d_in[6];
  const float* Wx_g   = (const float*)d_in[7];
  const float* bx_g   = (const float*)d_in[8];
  const float* Wh_g   = (const float*)d_in[9];
  const float* bh_g   = (const float*)d_in[10];
  float* out = (float*)d_out;

  char* ws = (char*)d_ws;
  unsigned short* GX2   = (unsigned short*)(ws);                 // 134217728 B (fp16 tiled)
  unsigned short* Xbf   = (unsigned short*)(ws + 134217728);     // 33554432
  unsigned short* WxGb  = (unsigned short*)(ws + 167772160);     // 8388608
  unsigned short* WhGb  = (unsigned short*)(ws + 176160768);     // 8388608
  unsigned short* WinT  = (unsigned short*)(ws + 184549376);     // 2097152 (reused for flags)
  unsigned short* WhidT = (unsigned short*)(ws + 186646528);     // 2097152
  unsigned short* Wxc   = (unsigned short*)(ws + 188743680);     // 8388608
  unsigned short* Whc   = (unsigned short*)(ws + 197132288);     // 8388608
  float*          gbias = (float*)(ws + 205520896);              // 16384
  unsigned short* hbuf  = (unsigned short*)(ws + 205537280);     // 262144
  unsigned*       flags = (unsigned*)(ws + 184549376);           // 1 MB (256 flags @ 4KB stride)

  // converts
  k_conv_bf16<<<16384, 256, 0, stream>>>(x, Xbf);
  k_conv_bf16<<<4096, 256, 0, stream>>>(Wx_g, WxGb);
  k_conv_bf16<<<4096, 256, 0, stream>>>(Wh_g, WhGb);
  k_transpose<<<dim3(32, 32), 256, 0, stream>>>(W_in, WinT, 1024, 1024);
  k_transpose<<<dim3(32, 32), 256, 0, stream>>>(W_hid, WhidT, 1024, 1024);
  // combined weights: Wxc = WxG @ W_in (via W_in^T), Whc = WhG @ W_hid
  k_gemm_bt<0><<<dim3(8, 32), 256, 0, stream>>>(WxGb, WinT, Wxc, nullptr, 4096, 1024, 1024);
  k_gemm_bt<0><<<dim3(8, 32), 256, 0, stream>>>(WhGb, WhidT, Whc, nullptr, 4096, 1024, 1024);
  k_bias<<<64, 256, 0, stream>>>(Wx_g, bx_g, b_in, Wh_g, bh_g, b_hid, gbias);
  // GX2 = tiled(X @ Wxc^T + gbias)  (fp16, per-(t,block) 8KB chunks)
  k_gemm_bt<1><<<dim3(32, 128), 256, 0, stream>>>(Xbf, Wxc, GX2, gbias, 16384, 4096, 1024);
  // h0
  k_conv_bf16<<<64, 256, 0, stream>>>(hidden, hbuf);
  // flags overlay WinT (its consumers are done); 4KB-spread
  hipMemsetAsync(flags, 0, 256 * 4096, stream);
  // sequential scan
  k_lstm_seq<<<SEQ_BLOCKS, 256, 0, stream>>>(GX2, Whc, cell, hbuf, out, flags);
}

// Round 5
// 2986.972 us; speedup vs baseline: 1.1482x; 1.1482x over previous
//
#include <hip/hip_runtime.h>

typedef __attribute__((ext_vector_type(8))) short short8;
typedef __attribute__((ext_vector_type(4))) float f32x4;

#define SEQ_BLOCKS 64

__device__ __forceinline__ unsigned short f2bf(float f) {
  unsigned u = __float_as_uint(f);
  u = u + 0x7fffu + ((u >> 16) & 1u);
  return (unsigned short)(u >> 16);
}
__device__ __forceinline__ unsigned short f2h(float f) {
  _Float16 h = (_Float16)f;
  unsigned short r;
  __builtin_memcpy(&r, &h, 2);
  return r;
}
__device__ __forceinline__ float h2f(unsigned short u) {
  _Float16 h;
  __builtin_memcpy(&h, &u, 2);
  return (float)h;
}
__device__ __forceinline__ void gload16(const void* g, void* l) {
  __builtin_amdgcn_global_load_lds(
      (const __attribute__((address_space(1))) unsigned int*)g,
      (__attribute__((address_space(3))) unsigned int*)l, 16, 0, 0);
}
__device__ __forceinline__ float fast_sigmoid(float x) {
  return 1.0f / (1.0f + __expf(-x));
}
__device__ __forceinline__ float fast_tanh(float x) {
  return 2.0f / (1.0f + __expf(-2.0f * x)) - 1.0f;
}
// 16B load that bypasses L1/L2 (relaxed agent atomics -> sc0 sc1, no inv/wbl2)
__device__ __forceinline__ short8 load_h16(const unsigned short* p) {
  union { unsigned long long u[2]; short8 s; } r;
  r.u[0] = __hip_atomic_load((const unsigned long long*)p, __ATOMIC_RELAXED,
                             __HIP_MEMORY_SCOPE_AGENT);
  r.u[1] = __hip_atomic_load(((const unsigned long long*)p) + 1, __ATOMIC_RELAXED,
                             __HIP_MEMORY_SCOPE_AGENT);
  return r.s;
}

// ---------- elementwise fp32 -> bf16 convert (vectorized) ----------
__global__ void k_conv_bf16(const float* __restrict__ in, unsigned short* __restrict__ out) {
  size_t i = ((size_t)blockIdx.x * 256 + threadIdx.x) * 4;
  float4 v = *(const float4*)(in + i);
  unsigned short o[4] = {f2bf(v.x), f2bf(v.y), f2bf(v.z), f2bf(v.w)};
  *(uint2*)(out + i) = *(const uint2*)o;
}

// ---------- transpose + convert: out[c][r] = bf16(in[r][c]) ----------
__global__ void k_transpose(const float* __restrict__ in, unsigned short* __restrict__ out,
                            int R, int C) {
  __shared__ float tile[32][33];
  int bx = blockIdx.x * 32, by = blockIdx.y * 32;
  int tx = threadIdx.x & 31, ty = threadIdx.x >> 5;  // ty 0..7
  for (int i = 0; i < 32; i += 8)
    tile[ty + i][tx] = in[(size_t)(by + ty + i) * C + bx + tx];
  __syncthreads();
  for (int i = 0; i < 32; i += 8)
    out[(size_t)(bx + ty + i) * R + by + tx] = f2bf(tile[tx][ty + i]);
}

// ---------- generic bf16 GEMM, C = A @ B^T (+bias), A[M][K], B[N][K] bf16 ----------
// OUTMODE 0: bf16 linear C[row][col]
// OUTMODE 1: fp16 tiled GX2[t][blk][g][b][jj]  (row = t*64+b, col = g*1024 + blk*16 + jj)
template<int OUTMODE>
__global__ __launch_bounds__(256) void k_gemm_bt(
    const unsigned short* __restrict__ A, const unsigned short* __restrict__ B,
    unsigned short* __restrict__ C, const float* __restrict__ bias,
    int M, int N, int K) {
  __shared__ unsigned short As[128 * 32];
  __shared__ unsigned short Bs[128 * 32];
  const int tid = threadIdx.x;
  const int wv = tid >> 6, l = tid & 63;
  const int m0 = blockIdx.y * 128, n0 = blockIdx.x * 128;
  const int wr = (wv >> 1) * 64, wc = (wv & 1) * 64;
  f32x4 acc[4][4] = {};
  for (int k0 = 0; k0 < K; k0 += 32) {
#pragma unroll
    for (int j = 0; j < 2; ++j) {
      int c = wv * 128 + j * 64 + l;
      int row = c >> 2, kc = (c & 3) * 8;
      gload16(A + (size_t)(m0 + row) * K + k0 + kc, (char*)As + c * 16);
      gload16(B + (size_t)(n0 + row) * K + k0 + kc, (char*)Bs + c * 16);
    }
    __syncthreads();
    short8 af[4], bfr[4];
#pragma unroll
    for (int rf = 0; rf < 4; ++rf)
      af[rf] = *(const short8*)(As + (wr + rf * 16 + (l & 15)) * 32 + (l >> 4) * 8);
#pragma unroll
    for (int cf = 0; cf < 4; ++cf)
      bfr[cf] = *(const short8*)(Bs + (wc + cf * 16 + (l & 15)) * 32 + (l >> 4) * 8);
#pragma unroll
    for (int rf = 0; rf < 4; ++rf)
#pragma unroll
      for (int cf = 0; cf < 4; ++cf)
        acc[rf][cf] = __builtin_amdgcn_mfma_f32_16x16x32_bf16(af[rf], bfr[cf], acc[rf][cf], 0, 0, 0);
    __syncthreads();
  }
#pragma unroll
  for (int cf = 0; cf < 4; ++cf) {
    int col = n0 + wc + cf * 16 + (l & 15);
    float bv = bias ? bias[col] : 0.0f;
#pragma unroll
    for (int rf = 0; rf < 4; ++rf) {
#pragma unroll
      for (int i = 0; i < 4; ++i) {
        int row = m0 + wr + rf * 16 + (l >> 4) * 4 + i;
        float v = acc[rf][cf][i] + bv;
        if (OUTMODE == 0) {
          C[(size_t)row * N + col] = f2bf(v);
        } else {
          int t = row >> 6, b = row & 63;
          int g = col >> 10, c = col & 1023;
          size_t idx = (size_t)(t * 64 + (c >> 4)) * 4096 + (g * 64 + b) * 16 + (c & 15);
          C[idx] = f2h(v);
        }
      }
    }
  }
}

// ---------- combined bias ----------
__global__ void k_bias(const float* __restrict__ Wxg, const float* __restrict__ bxg,
                       const float* __restrict__ b_in, const float* __restrict__ Whg,
                       const float* __restrict__ bhg, const float* __restrict__ b_hid,
                       float* __restrict__ gbias) {
  int col = blockIdx.x * 64 + (threadIdx.x >> 2);
  int p = threadIdx.x & 3;
  const float* wx = Wxg + (size_t)col * 1024;
  const float* wh = Whg + (size_t)col * 1024;
  float s = 0.f;
  for (int k = p * 256; k < p * 256 + 256; ++k)
    s += wx[k] * b_in[k] + wh[k] * b_hid[k];
  s += __shfl_down(s, 2, 4);
  s += __shfl_down(s, 1, 4);
  if (p == 0) gbias[col] = s + bxg[col] + bhg[col];
}

// ---------- persistent sequential LSTM scan (weights-in-VGPR, k-split) ----------
// 64 blocks x 4 waves. Block owns h-cols [bid*16,+16) (64 gate-cols).
// Wave wv owns k in [wv*256,+256): its weight B-fragments live in 128 VGPRs
// (loaded ONCE). Per step: wave loads all 64 h-rows x its k-quarter from L3,
// does 128 MFMA from registers (NO LDS reads in the hot loop), writes f32
// partials to a double-buffered LDS pbuf; ONE __syncthreads; each thread
// sums the 4 wave-partials for its 16 gate values, applies gates, stores h.
// Sync: per-(block,wave) flags; wave wv polls its 16 source blocks x 4 waves
// (64 flags, 256B apart, s_sleep backoff). hbuf is 4-deep: two-hop flag
// transitivity guarantees all readers of h(t) finished before h(t+3) lands.
__global__ __launch_bounds__(256, 1) void k_lstm_seq(
    const unsigned short* __restrict__ GX2,  // fp16 tiled [256][64][4][64][16]
    const unsigned short* __restrict__ Whc,  // bf16 [4096][1024]
    const float* __restrict__ cell,          // [64][1024] f32
    unsigned short* __restrict__ hbuf,       // bf16 [4][64][1024]
    float* __restrict__ out,                 // h [64][1024], c [64][1024] f32
    unsigned* __restrict__ flags) {          // 256 wave-flags, stride 64 u32
  __shared__ float pbuf[2][64 * 260];        // 133 KB, rotation-swizzled
  const int tid = threadIdx.x;
  const int wv = tid >> 6, l = tid & 63;
  const int bid = blockIdx.x;

  // ---- load this wave's weight fragments into VGPRs (once) ----
  // w[ct][u]: gate-col = ct*16 + (l&15) of block, k = wv*256 + u*32 + (l>>4)*8
  short8 w[4][8];
#pragma unroll
  for (int ct = 0; ct < 4; ++ct)
#pragma unroll
    for (int u = 0; u < 8; ++u)
      w[ct][u] = *(const short8*)(
          Whc + (size_t)(ct * 1024 + bid * 16 + (l & 15)) * 1024 +
          wv * 256 + u * 32 + (l >> 4) * 8);

  // elementwise ownership: batch-row eb, h-cols ej..ej+3
  const int eb = tid >> 2;
  const int ej = (tid & 3) * 4;
  float c_reg[4];
  {
    float4 c4 = *(const float4*)(cell + (size_t)eb * 1024 + bid * 16 + ej);
    c_reg[0] = c4.x; c_reg[1] = c4.y; c_reg[2] = c4.z; c_reg[3] = c4.w;
  }

  unsigned* myflag = flags + (bid * 4 + wv) * 64;
  // poll set: lane l <-> (source block 16*wv + (l>>2), wave l&3)
  const unsigned* pollflag = flags + (((16 * wv + (l >> 2)) * 4) + (l & 3)) * 64;

  for (int t = 0; t < 256; ++t) {
    // --- GX prefetch for this thread's gate values (plain loads, hide in poll) ---
    const unsigned short* chunk = GX2 + ((size_t)t * 64 + bid) * 4096;
    unsigned long long gxu[4];
#pragma unroll
    for (int g = 0; g < 4; ++g)
      gxu[g] = *(const unsigned long long*)(chunk + (g * 64 + eb) * 16 + ej);

    // --- wait for h(t): poll 64 source wave-flags (relaxed, backoff) ---
    if (t > 0) {
      const unsigned tgt = (unsigned)t;
      for (;;) {
        unsigned v = __hip_atomic_load(pollflag, __ATOMIC_RELAXED, __HIP_MEMORY_SCOPE_AGENT);
        if (__all((int)(v >= tgt))) break;
        __builtin_amdgcn_s_sleep(1);
      }
      __builtin_amdgcn_fence(__ATOMIC_ACQUIRE, "workgroup");
    }

    // --- load A: all 64 batch-rows x this wave's k-quarter, from L3 ---
    const unsigned short* hb = hbuf + (size_t)(t & 3) * 65536 + wv * 256 + (l >> 4) * 8;
    short8 a[4][8];
#pragma unroll
    for (int rt = 0; rt < 4; ++rt)
#pragma unroll
      for (int u = 0; u < 8; ++u)
        a[rt][u] = load_h16(hb + (size_t)(rt * 16 + (l & 15)) * 1024 + u * 32);

    // --- 128 MFMA, all operands in registers ---
    f32x4 acc[4][4] = {};
#pragma unroll
    for (int u = 0; u < 8; ++u)
#pragma unroll
      for (int rt = 0; rt < 4; ++rt)
#pragma unroll
        for (int ct = 0; ct < 4; ++ct)
          acc[rt][ct] = __builtin_amdgcn_mfma_f32_16x16x32_bf16(a[rt][u], w[ct][u],
                                                                acc[rt][ct], 0, 0, 0);

    // --- write partials to LDS (rotation swizzle: gcr = (gc + 4*b) & 63) ---
    float* pb = pbuf[t & 1];
#pragma unroll
    for (int rt = 0; rt < 4; ++rt)
#pragma unroll
      for (int ct = 0; ct < 4; ++ct)
#pragma unroll
        for (int i = 0; i < 4; ++i) {
          int b = rt * 16 + (l >> 4) * 4 + i;
          int gc = ct * 16 + (l & 15);
          int gcr = (gc + 4 * b) & 63;
          pb[b * 260 + gcr * 4 + wv] = acc[rt][ct][i];
        }
    __syncthreads();

    // --- reduce 4 partials + GX, apply gates for (eb, ej..ej+3) ---
    float sgate[4][4];
#pragma unroll
    for (int g = 0; g < 4; ++g) {
      unsigned short gx4[4];
      __builtin_memcpy(gx4, &gxu[g], 8);
#pragma unroll
      for (int i2 = 0; i2 < 4; ++i2) {
        int gc = g * 16 + ej + i2;
        int gcr = (gc + 4 * eb) & 63;
        f32x4 p = *(const f32x4*)&pb[eb * 260 + gcr * 4];
        sgate[g][i2] = p[0] + p[1] + p[2] + p[3] + h2f(gx4[i2]);
      }
    }
    float hnew[4];
#pragma unroll
    for (int i2 = 0; i2 < 4; ++i2) {
      float ig = fast_sigmoid(sgate[0][i2]);
      float fg = fast_sigmoid(sgate[1][i2]);
      float gg = fast_tanh(sgate[2][i2]);
      float og = fast_sigmoid(sgate[3][i2]);
      c_reg[i2] = fg * c_reg[i2] + ig * gg;
      hnew[i2] = og * fast_tanh(c_reg[i2]);
    }

    if (t == 255) {
      float4 h4 = {hnew[0], hnew[1], hnew[2], hnew[3]};
      float4 c4 = {c_reg[0], c_reg[1], c_reg[2], c_reg[3]};
      *(float4*)(out + (size_t)eb * 1024 + bid * 16 + ej) = h4;
      *(float4*)(out + 65536 + (size_t)eb * 1024 + bid * 16 + ej) = c4;
    } else {
      // write-through h(t+1) to L3 (packed u64, relaxed agent = sc0 sc1)
      unsigned short hs[4] = {f2bf(hnew[0]), f2bf(hnew[1]), f2bf(hnew[2]), f2bf(hnew[3])};
      unsigned long long hv;
      __builtin_memcpy(&hv, hs, 8);
      __hip_atomic_store(
          (unsigned long long*)(hbuf + (size_t)((t + 1) & 3) * 65536 + (size_t)eb * 1024 +
                                bid * 16 + ej),
          hv, __ATOMIC_RELAXED, __HIP_MEMORY_SCOPE_AGENT);
      asm volatile("s_waitcnt vmcnt(0)" ::: "memory");  // this wave's h at L3
      if (l == 0)
        __hip_atomic_store(myflag, (unsigned)(t + 1), __ATOMIC_RELAXED,
                           __HIP_MEMORY_SCOPE_AGENT);
    }
  }
}

extern "C" void kernel_launch(void* const* d_in, const int* in_sizes, int n_in,
                              void* d_out, int out_size, void* d_ws, size_t ws_size,
                              hipStream_t stream) {
  const float* x      = (const float*)d_in[0];
  const float* hidden = (const float*)d_in[1];
  const float* cell   = (const float*)d_in[2];
  const float* W_in   = (const float*)d_in[3];
  const float* b_in   = (const float*)d_in[4];
  const float* W_hid  = (const float*)d_in[5];
  const float* b_hid  = (const float*)d_in[6];
  const float* Wx_g   = (const float*)d_in[7];
  const float* bx_g   = (const float*)d_in[8];
  const float* Wh_g   = (const float*)d_in[9];
  const float* bh_g   = (const float*)d_in[10];
  float* out = (float*)d_out;

  char* ws = (char*)d_ws;
  unsigned short* GX2   = (unsigned short*)(ws);                 // 134217728 B (fp16 tiled)
  unsigned short* Xbf   = (unsigned short*)(ws + 134217728);     // 33554432 (freed after GX gemm)
  unsigned short* WxGb  = (unsigned short*)(ws + 167772160);     // 8388608
  unsigned short* WhGb  = (unsigned short*)(ws + 176160768);     // 8388608
  unsigned short* WinT  = (unsigned short*)(ws + 184549376);     // 2097152 (reused for flags)
  unsigned short* WhidT = (unsigned short*)(ws + 186646528);     // 2097152
  unsigned short* Wxc   = (unsigned short*)(ws + 188743680);     // 8388608
  unsigned short* Whc   = (unsigned short*)(ws + 197132288);     // 8388608
  float*          gbias = (float*)(ws + 205520896);              // 16384
  unsigned short* hbuf  = (unsigned short*)(ws + 134217728);     // 524288 (overlays Xbf)
  unsigned*       flags = (unsigned*)(ws + 184549376);           // 65536 (overlays WinT)

  // converts
  k_conv_bf16<<<16384, 256, 0, stream>>>(x, Xbf);
  k_conv_bf16<<<4096, 256, 0, stream>>>(Wx_g, WxGb);
  k_conv_bf16<<<4096, 256, 0, stream>>>(Wh_g, WhGb);
  k_transpose<<<dim3(32, 32), 256, 0, stream>>>(W_in, WinT, 1024, 1024);
  k_transpose<<<dim3(32, 32), 256, 0, stream>>>(W_hid, WhidT, 1024, 1024);
  // combined weights: Wxc = WxG @ W_in (via W_in^T), Whc = WhG @ W_hid
  k_gemm_bt<0><<<dim3(8, 32), 256, 0, stream>>>(WxGb, WinT, Wxc, nullptr, 4096, 1024, 1024);
  k_gemm_bt<0><<<dim3(8, 32), 256, 0, stream>>>(WhGb, WhidT, Whc, nullptr, 4096, 1024, 1024);
  k_bias<<<64, 256, 0, stream>>>(Wx_g, bx_g, b_in, Wh_g, bh_g, b_hid, gbias);
  // GX2 = tiled(X @ Wxc^T + gbias)  (fp16, per-(t,block) 8KB chunks)
  k_gemm_bt<1><<<dim3(32, 128), 256, 0, stream>>>(Xbf, Wxc, GX2, gbias, 16384, 4096, 1024);
  // h0 into hbuf[0] (overlays Xbf — Xbf consumers all done above)
  k_conv_bf16<<<64, 256, 0, stream>>>(hidden, hbuf);
  // flags overlay WinT (its consumers are done)
  hipMemsetAsync(flags, 0, 256 * 64 * sizeof(unsigned), stream);
  // sequential scan
  k_lstm_seq<<<SEQ_BLOCKS, 256, 0, stream>>>(GX2, Whc, cell, hbuf, out, flags);
}

// Round 6
// 2131.650 us; speedup vs baseline: 1.6090x; 1.4012x over previous
//
#include <hip/hip_runtime.h>

typedef __attribute__((ext_vector_type(8))) short short8;
typedef __attribute__((ext_vector_type(4))) float f32x4;

#define SEQ_BLOCKS 64

__device__ __forceinline__ unsigned short f2bf(float f) {
  unsigned u = __float_as_uint(f);
  u = u + 0x7fffu + ((u >> 16) & 1u);
  return (unsigned short)(u >> 16);
}
__device__ __forceinline__ unsigned short f2h(float f) {
  _Float16 h = (_Float16)f;
  unsigned short r;
  __builtin_memcpy(&r, &h, 2);
  return r;
}
__device__ __forceinline__ float h2f(unsigned short u) {
  _Float16 h;
  __builtin_memcpy(&h, &u, 2);
  return (float)h;
}
__device__ __forceinline__ void gload16(const void* g, void* l) {
  __builtin_amdgcn_global_load_lds(
      (const __attribute__((address_space(1))) unsigned int*)g,
      (__attribute__((address_space(3))) unsigned int*)l, 16, 0, 0);
}
__device__ __forceinline__ float fast_sigmoid(float x) {
  return 1.0f / (1.0f + __expf(-x));
}
__device__ __forceinline__ float fast_tanh(float x) {
  return 2.0f / (1.0f + __expf(-2.0f * x)) - 1.0f;
}
// 16B load that bypasses L1/L2 (relaxed agent atomics -> sc0 sc1, no inv/wbl2)
__device__ __forceinline__ short8 load_h16(const unsigned short* p) {
  union { unsigned long long u[2]; short8 s; } r;
  r.u[0] = __hip_atomic_load((const unsigned long long*)p, __ATOMIC_RELAXED,
                             __HIP_MEMORY_SCOPE_AGENT);
  r.u[1] = __hip_atomic_load(((const unsigned long long*)p) + 1, __ATOMIC_RELAXED,
                             __HIP_MEMORY_SCOPE_AGENT);
  return r.s;
}

// ---------- elementwise fp32 -> bf16 convert (vectorized) ----------
__global__ void k_conv_bf16(const float* __restrict__ in, unsigned short* __restrict__ out) {
  size_t i = ((size_t)blockIdx.x * 256 + threadIdx.x) * 4;
  float4 v = *(const float4*)(in + i);
  unsigned short o[4] = {f2bf(v.x), f2bf(v.y), f2bf(v.z), f2bf(v.w)};
  *(uint2*)(out + i) = *(const uint2*)o;
}

// ---------- h0 into transposed hT[0][sb][row][16] ----------
__global__ void k_h0t(const float* __restrict__ hidden, unsigned short* __restrict__ hT) {
  int sb = blockIdx.x;
  int row = threadIdx.x >> 2, c4 = (threadIdx.x & 3) * 4;
  float4 v = *(const float4*)(hidden + (size_t)row * 1024 + sb * 16 + c4);
  unsigned short o[4] = {f2bf(v.x), f2bf(v.y), f2bf(v.z), f2bf(v.w)};
  unsigned long long u;
  __builtin_memcpy(&u, o, 8);
  *(unsigned long long*)(hT + (size_t)sb * 1024 + row * 16 + c4) = u;
}

// ---------- transpose + convert: out[c][r] = bf16(in[r][c]) ----------
__global__ void k_transpose(const float* __restrict__ in, unsigned short* __restrict__ out,
                            int R, int C) {
  __shared__ float tile[32][33];
  int bx = blockIdx.x * 32, by = blockIdx.y * 32;
  int tx = threadIdx.x & 31, ty = threadIdx.x >> 5;  // ty 0..7
  for (int i = 0; i < 32; i += 8)
    tile[ty + i][tx] = in[(size_t)(by + ty + i) * C + bx + tx];
  __syncthreads();
  for (int i = 0; i < 32; i += 8)
    out[(size_t)(bx + ty + i) * R + by + tx] = f2bf(tile[tx][ty + i]);
}

// ---------- generic bf16 GEMM, C = A @ B^T (+bias), A[M][K], B[N][K] bf16 ----------
// OUTMODE 0: bf16 linear C[row][col]
// OUTMODE 1: fp16 tiled GX2[t][blk][g][b][jj]  (row = t*64+b, col = g*1024 + blk*16 + jj)
template<int OUTMODE>
__global__ __launch_bounds__(256) void k_gemm_bt(
    const unsigned short* __restrict__ A, const unsigned short* __restrict__ B,
    unsigned short* __restrict__ C, const float* __restrict__ bias,
    int M, int N, int K) {
  __shared__ unsigned short As[128 * 32];
  __shared__ unsigned short Bs[128 * 32];
  const int tid = threadIdx.x;
  const int wv = tid >> 6, l = tid & 63;
  const int m0 = blockIdx.y * 128, n0 = blockIdx.x * 128;
  const int wr = (wv >> 1) * 64, wc = (wv & 1) * 64;
  f32x4 acc[4][4] = {};
  for (int k0 = 0; k0 < K; k0 += 32) {
#pragma unroll
    for (int j = 0; j < 2; ++j) {
      int c = wv * 128 + j * 64 + l;
      int row = c >> 2, kc = (c & 3) * 8;
      gload16(A + (size_t)(m0 + row) * K + k0 + kc, (char*)As + c * 16);
      gload16(B + (size_t)(n0 + row) * K + k0 + kc, (char*)Bs + c * 16);
    }
    __syncthreads();
    short8 af[4], bfr[4];
#pragma unroll
    for (int rf = 0; rf < 4; ++rf)
      af[rf] = *(const short8*)(As + (wr + rf * 16 + (l & 15)) * 32 + (l >> 4) * 8);
#pragma unroll
    for (int cf = 0; cf < 4; ++cf)
      bfr[cf] = *(const short8*)(Bs + (wc + cf * 16 + (l & 15)) * 32 + (l >> 4) * 8);
#pragma unroll
    for (int rf = 0; rf < 4; ++rf)
#pragma unroll
      for (int cf = 0; cf < 4; ++cf)
        acc[rf][cf] = __builtin_amdgcn_mfma_f32_16x16x32_bf16(af[rf], bfr[cf], acc[rf][cf], 0, 0, 0);
    __syncthreads();
  }
#pragma unroll
  for (int cf = 0; cf < 4; ++cf) {
    int col = n0 + wc + cf * 16 + (l & 15);
    float bv = bias ? bias[col] : 0.0f;
#pragma unroll
    for (int rf = 0; rf < 4; ++rf) {
#pragma unroll
      for (int i = 0; i < 4; ++i) {
        int row = m0 + wr + rf * 16 + (l >> 4) * 4 + i;
        float v = acc[rf][cf][i] + bv;
        if (OUTMODE == 0) {
          C[(size_t)row * N + col] = f2bf(v);
        } else {
          int t = row >> 6, b = row & 63;
          int g = col >> 10, c = col & 1023;
          size_t idx = (size_t)(t * 64 + (c >> 4)) * 4096 + (g * 64 + b) * 16 + (c & 15);
          C[idx] = f2h(v);
        }
      }
    }
  }
}

// ---------- combined bias ----------
__global__ void k_bias(const float* __restrict__ Wxg, const float* __restrict__ bxg,
                       const float* __restrict__ b_in, const float* __restrict__ Whg,
                       const float* __restrict__ bhg, const float* __restrict__ b_hid,
                       float* __restrict__ gbias) {
  int col = blockIdx.x * 64 + (threadIdx.x >> 2);
  int p = threadIdx.x & 3;
  const float* wx = Wxg + (size_t)col * 1024;
  const float* wh = Whg + (size_t)col * 1024;
  float s = 0.f;
  for (int k = p * 256; k < p * 256 + 256; ++k)
    s += wx[k] * b_in[k] + wh[k] * b_hid[k];
  s += __shfl_down(s, 2, 4);
  s += __shfl_down(s, 1, 4);
  if (p == 0) gbias[col] = s + bxg[col] + bhg[col];
}

// ---------- persistent sequential LSTM scan ----------
// 64 blocks x 4 waves. Block owns gate-cols [bid*16,+16) per gate; wave wv owns
// k-quarter [wv*256,+256) with weights in 128 VGPRs (loaded once).
// h exchange via TRANSPOSED hT[4][src 64][row 64][col 16] bf16: each block's
// message is ONE contiguous 2KB (16 lines). One tag per block (poll = 16 lines
// per wave, s_sleep backoff). All cross-block traffic sc0/sc1 (L3-only).
// Depth-4 hT + block-level tag join gives transitive anti-overwrite safety.
__global__ __launch_bounds__(256, 1) void k_lstm_seq(
    const unsigned short* __restrict__ GX2,  // fp16 tiled [256][64][4][64][16]
    const unsigned short* __restrict__ Whc,  // bf16 [4096][1024]
    const float* __restrict__ cell,          // [64][1024] f32
    unsigned short* __restrict__ hT,         // bf16 [4][64][64][16]
    float* __restrict__ out,                 // h [64][1024], c [64][1024] f32
    unsigned* __restrict__ flags) {          // 64 tags, stride 64 u32 (256B)
  __shared__ float pbuf[64 * 261 + 4];       // ~67 KB, slot-rotated
  const int tid = threadIdx.x;
  const int wv = tid >> 6, l = tid & 63;
  const int bid = blockIdx.x;

  // ---- weights into VGPRs: w[ct][u] = gate-col ct*16+(l&15), k = wv*256+u*32+(l>>4)*8
  short8 w[4][8];
#pragma unroll
  for (int ct = 0; ct < 4; ++ct)
#pragma unroll
    for (int u = 0; u < 8; ++u)
      w[ct][u] = *(const short8*)(
          Whc + (size_t)(ct * 1024 + bid * 16 + (l & 15)) * 1024 +
          wv * 256 + u * 32 + (l >> 4) * 8);

  // elementwise ownership: batch-row eb, h-cols ej..ej+3
  const int eb = tid >> 2;
  const int ej = (tid & 3) * 4;
  float c_reg[4];
  {
    float4 c4 = *(const float4*)(cell + (size_t)eb * 1024 + bid * 16 + ej);
    c_reg[0] = c4.x; c_reg[1] = c4.y; c_reg[2] = c4.z; c_reg[3] = c4.w;
  }

  // A-load base: sb = wv*16 + ((l>>4)>>1), row-part (l&15)*16, col8 = ((l>>4)&1)*8
  const size_t abase = (size_t)(wv * 16 + ((l >> 4) >> 1)) * 1024 + (l & 15) * 16 +
                       ((l >> 4) & 1) * 8;
  const unsigned* pollp = flags + (16 * wv + (l & 15)) * 64;

  for (int t = 0; t < 256; ++t) {
    // --- GX prefetch (plain loads, L2-cached; hides under poll) ---
    const unsigned short* chunk = GX2 + ((size_t)t * 64 + bid) * 4096;
    unsigned long long gxu[4];
#pragma unroll
    for (int g = 0; g < 4; ++g)
      gxu[g] = *(const unsigned long long*)(chunk + (g * 64 + eb) * 16 + ej);

    // --- wait for the 16 source-block tags of this wave's k-quarter ---
    if (t > 0) {
      const unsigned tgt = (unsigned)t;
      for (;;) {
        unsigned v = __hip_atomic_load(pollp, __ATOMIC_RELAXED, __HIP_MEMORY_SCOPE_AGENT);
        if (__all((int)(v >= tgt))) break;
        __builtin_amdgcn_s_sleep(1);
      }
      __builtin_amdgcn_fence(__ATOMIC_ACQUIRE, "workgroup");
    }

    // --- load A from compact hT messages (L3-only) ---
    const unsigned short* hb = hT + ((size_t)(t & 3) << 16) + abase;
    short8 a[4][8];
#pragma unroll
    for (int u = 0; u < 8; ++u)
#pragma unroll
      for (int rt = 0; rt < 4; ++rt)
        a[rt][u] = load_h16(hb + u * 2048 + rt * 256);

    // --- 128 MFMA, all operands in registers ---
    f32x4 acc[4][4] = {};
#pragma unroll
    for (int u = 0; u < 8; ++u)
#pragma unroll
      for (int rt = 0; rt < 4; ++rt)
#pragma unroll
        for (int ct = 0; ct < 4; ++ct)
          acc[rt][ct] = __builtin_amdgcn_mfma_f32_16x16x32_bf16(a[rt][u], w[ct][u],
                                                                acc[rt][ct], 0, 0, 0);

    // --- partials to LDS: addr = b*261 + gc*4 + slot, slot = (wv+gc+(b>>2))&3 ---
#pragma unroll
    for (int rt = 0; rt < 4; ++rt)
#pragma unroll
      for (int ct = 0; ct < 4; ++ct)
#pragma unroll
        for (int i = 0; i < 4; ++i) {
          int b = rt * 16 + (l >> 4) * 4 + i;
          int gc = ct * 16 + (l & 15);
          int slot = (wv + gc + (b >> 2)) & 3;
          pbuf[b * 261 + gc * 4 + slot] = acc[rt][ct][i];
        }
    __syncthreads();

    // --- reduce 4 slots + GX, apply gates for (eb, ej..ej+3) ---
    float sgate[4][4];
#pragma unroll
    for (int g = 0; g < 4; ++g) {
      unsigned short gx4[4];
      __builtin_memcpy(gx4, &gxu[g], 8);
#pragma unroll
      for (int i2 = 0; i2 < 4; ++i2) {
        int gc = g * 16 + ej + i2;
        f32x4 p = *(const f32x4*)&pbuf[eb * 261 + gc * 4];
        sgate[g][i2] = p[0] + p[1] + p[2] + p[3] + h2f(gx4[i2]);
      }
    }
    float hnew[4];
#pragma unroll
    for (int i2 = 0; i2 < 4; ++i2) {
      float ig = fast_sigmoid(sgate[0][i2]);
      float fg = fast_sigmoid(sgate[1][i2]);
      float gg = fast_tanh(sgate[2][i2]);
      float og = fast_sigmoid(sgate[3][i2]);
      c_reg[i2] = fg * c_reg[i2] + ig * gg;
      hnew[i2] = og * fast_tanh(c_reg[i2]);
    }

    if (t == 255) {
      float4 h4 = {hnew[0], hnew[1], hnew[2], hnew[3]};
      float4 c4 = {c_reg[0], c_reg[1], c_reg[2], c_reg[3]};
      *(float4*)(out + (size_t)eb * 1024 + bid * 16 + ej) = h4;
      *(float4*)(out + 65536 + (size_t)eb * 1024 + bid * 16 + ej) = c4;
      __syncthreads();  // keep barrier count uniform (paranoia; last step)
    } else {
      // h(t+1) message: contiguous 2KB at hT[(t+1)&3][bid]
      unsigned short hs[4] = {f2bf(hnew[0]), f2bf(hnew[1]), f2bf(hnew[2]), f2bf(hnew[3])};
      unsigned long long hv;
      __builtin_memcpy(&hv, hs, 8);
      __hip_atomic_store(
          (unsigned long long*)(hT + ((size_t)((t + 1) & 3) << 16) + (size_t)bid * 1024 +
                                eb * 16 + ej),
          hv, __ATOMIC_RELAXED, __HIP_MEMORY_SCOPE_AGENT);
      asm volatile("s_waitcnt vmcnt(0)" ::: "memory");  // this wave's stores at L3
      __syncthreads();                                   // all 4 waves' stores done
      if (tid == 0)
        __hip_atomic_store(&flags[bid * 64], (unsigned)(t + 1), __ATOMIC_RELAXED,
                           __HIP_MEMORY_SCOPE_AGENT);
    }
  }
}

extern "C" void kernel_launch(void* const* d_in, const int* in_sizes, int n_in,
                              void* d_out, int out_size, void* d_ws, size_t ws_size,
                              hipStream_t stream) {
  const float* x      = (const float*)d_in[0];
  const float* hidden = (const float*)d_in[1];
  const float* cell   = (const float*)d_in[2];
  const float* W_in   = (const float*)d_in[3];
  const float* b_in   = (const float*)d_in[4];
  const float* W_hid  = (const float*)d_in[5];
  const float* b_hid  = (const float*)d_in[6];
  const float* Wx_g   = (const float*)d_in[7];
  const float* bx_g   = (const float*)d_in[8];
  const float* Wh_g   = (const float*)d_in[9];
  const float* bh_g   = (const float*)d_in[10];
  float* out = (float*)d_out;

  char* ws = (char*)d_ws;
  unsigned short* GX2   = (unsigned short*)(ws);                 // 134217728 B (fp16 tiled)
  unsigned short* Xbf   = (unsigned short*)(ws + 134217728);     // 33554432 (freed after GX gemm)
  unsigned short* WxGb  = (unsigned short*)(ws + 167772160);     // 8388608
  unsigned short* WhGb  = (unsigned short*)(ws + 176160768);     // 8388608
  unsigned short* WinT  = (unsigned short*)(ws + 184549376);     // 2097152 (reused for flags)
  unsigned short* WhidT = (unsigned short*)(ws + 186646528);     // 2097152
  unsigned short* Wxc   = (unsigned short*)(ws + 188743680);     // 8388608
  unsigned short* Whc   = (unsigned short*)(ws + 197132288);     // 8388608
  float*          gbias = (float*)(ws + 205520896);              // 16384
  unsigned short* hT    = (unsigned short*)(ws + 134217728);     // 1 MB (overlays Xbf)
  unsigned*       flags = (unsigned*)(ws + 184549376);           // 16 KB (overlays WinT)

  // converts
  k_conv_bf16<<<16384, 256, 0, stream>>>(x, Xbf);
  k_conv_bf16<<<4096, 256, 0, stream>>>(Wx_g, WxGb);
  k_conv_bf16<<<4096, 256, 0, stream>>>(Wh_g, WhGb);
  k_transpose<<<dim3(32, 32), 256, 0, stream>>>(W_in, WinT, 1024, 1024);
  k_transpose<<<dim3(32, 32), 256, 0, stream>>>(W_hid, WhidT, 1024, 1024);
  // combined weights: Wxc = WxG @ W_in (via W_in^T), Whc = WhG @ W_hid
  k_gemm_bt<0><<<dim3(8, 32), 256, 0, stream>>>(WxGb, WinT, Wxc, nullptr, 4096, 1024, 1024);
  k_gemm_bt<0><<<dim3(8, 32), 256, 0, stream>>>(WhGb, WhidT, Whc, nullptr, 4096, 1024, 1024);
  k_bias<<<64, 256, 0, stream>>>(Wx_g, bx_g, b_in, Wh_g, bh_g, b_hid, gbias);
  // GX2 = tiled(X @ Wxc^T + gbias)  (fp16, per-(t,block) 8KB chunks)
  k_gemm_bt<1><<<dim3(32, 128), 256, 0, stream>>>(Xbf, Wxc, GX2, gbias, 16384, 4096, 1024);
  // h0 into transposed hT[0] (overlays Xbf — all Xbf consumers done above)
  k_h0t<<<64, 256, 0, stream>>>(hidden, hT);
  // flags overlay WinT (consumers done)
  hipMemsetAsync(flags, 0, 64 * 64 * sizeof(unsigned), stream);
  // sequential scan
  k_lstm_seq<<<SEQ_BLOCKS, 256, 0, stream>>>(GX2, Whc, cell, hT, out, flags);
}